// Round 2
// baseline (2126.785 us; speedup 1.0000x reference)
//
#include <hip/hip_runtime.h>
#include <hip/hip_bf16.h>
#include <cstdint>
#include <cstddef>

#define N_NODES 100000
#define N_EDGES 3200000
#define D 256
#define SCAN_BLOCKS 391   // ceil(100000/256)

// ---------------------------------------------------------------------------
// CSR build: count -> scan -> fill
// NOTE: edge_index arrives as int32 (harness converts all integer inputs to
// int32), NOT int64 as in the JAX reference. Reading it as long long was the
// round-1 core dump.
// ---------------------------------------------------------------------------
__global__ void count_kernel(const int* __restrict__ tgt, int* __restrict__ cnt) {
    int e = blockIdx.x * blockDim.x + threadIdx.x;
    if (e < N_EDGES) {
        int t = tgt[e];
        if (t >= 0 && t < N_NODES) atomicAdd(&cnt[t], 1);
    }
}

__global__ void scan1_kernel(const int* __restrict__ cnt, int* __restrict__ offs,
                             int* __restrict__ bsum) {
    __shared__ int s[256];
    int t = threadIdx.x;
    int i = blockIdx.x * 256 + t;
    int v = (i < N_NODES) ? cnt[i] : 0;
    s[t] = v;
    __syncthreads();
    for (int d = 1; d < 256; d <<= 1) {
        int x = (t >= d) ? s[t - d] : 0;
        __syncthreads();
        s[t] += x;
        __syncthreads();
    }
    if (i < N_NODES) offs[i + 1] = s[t];      // block-local inclusive
    if (t == 255) bsum[blockIdx.x] = s[255];  // block total
}

__global__ void scan2_kernel(int* __restrict__ bsum) {
    __shared__ int s[512];
    int t = threadIdx.x;
    int v = (t < SCAN_BLOCKS) ? bsum[t] : 0;
    s[t] = v;
    __syncthreads();
    for (int d = 1; d < 512; d <<= 1) {
        int x = (t >= d) ? s[t - d] : 0;
        __syncthreads();
        s[t] += x;
        __syncthreads();
    }
    if (t < SCAN_BLOCKS) bsum[t] = (t == 0) ? 0 : s[t - 1];  // exclusive block offset
}

__global__ void scan3_kernel(int* __restrict__ offs, const int* __restrict__ bsum) {
    int t = threadIdx.x;
    int i = blockIdx.x * 256 + t;
    if (i < N_NODES) offs[i + 1] += bsum[blockIdx.x];
    if (i == 0) offs[0] = 0;
}

__global__ void cursor_kernel(const int* __restrict__ offs, int* __restrict__ cursor) {
    int i = blockIdx.x * 256 + threadIdx.x;
    if (i < N_NODES) cursor[i] = offs[i];
}

__global__ void fill_kernel(const int* __restrict__ src,
                            const int* __restrict__ tgt,
                            int* __restrict__ cursor, int* __restrict__ sorted_src) {
    int e = blockIdx.x * blockDim.x + threadIdx.x;
    if (e < N_EDGES) {
        int t = tgt[e];
        int s = src[e];
        if (t >= 0 && t < N_NODES && s >= 0 && s < N_NODES) {
            int p = atomicAdd(&cursor[t], 1);
            sorted_src[p] = s;
        }
    }
}

// ---------------------------------------------------------------------------
// Mean aggregation: one wave per node, lane covers float4 (256 cols / 64 lanes)
// ---------------------------------------------------------------------------
__global__ __launch_bounds__(256) void aggregate_kernel(
    const float* __restrict__ in, float* __restrict__ out,
    const int* __restrict__ offs, const int* __restrict__ sorted_src) {
    int node = blockIdx.x * 4 + (threadIdx.x >> 6);
    if (node >= N_NODES) return;
    int lane = threadIdx.x & 63;
    int beg = offs[node], end = offs[node + 1];
    float4 acc = {0.f, 0.f, 0.f, 0.f};
    for (int j = beg; j < end; ++j) {
        int s = sorted_src[j];
        const float4 v = *(const float4*)(in + (size_t)s * D + lane * 4);
        acc.x += v.x; acc.y += v.y; acc.z += v.z; acc.w += v.w;
    }
    float inv = 1.0f / fmaxf((float)(end - beg), 1.0f);
    float4 r = {acc.x * inv, acc.y * inv, acc.z * inv, acc.w * inv};
    *(float4*)(out + (size_t)node * D + lane * 4) = r;
}

// ---------------------------------------------------------------------------
// Fused GEMM: out = [A0 | A1] @ [B0 ; B1] + bias  (K = 512), optional ReLU.
// BM=BN=64, BK=16, 256 threads, 4x4 microtile per thread.
// ---------------------------------------------------------------------------
__global__ __launch_bounds__(256) void gemm_fused(
    const float* __restrict__ A0, const float* __restrict__ A1,
    const float* __restrict__ B0, const float* __restrict__ B1,
    const float* __restrict__ bias, float* __restrict__ out, int relu) {
    __shared__ float As[16][64];
    __shared__ float Bs[16][64];
    const int m0 = blockIdx.y * 64, n0 = blockIdx.x * 64;
    const int t = threadIdx.x;
    const int tx = t & 15, ty = t >> 4;
    const int a_row = t >> 2;        // 0..63
    const int a_k4  = (t & 3) * 4;   // 0,4,8,12
    const int b_row = t >> 4;        // 0..15
    const int b_n4  = (t & 15) * 4;  // 0..60
    float acc[4][4] = {};

    for (int k0 = 0; k0 < 512; k0 += 16) {
        const float* A = (k0 < 256) ? A0 : A1;
        const float* B = (k0 < 256) ? B0 : B1;
        const int kk = k0 & 255;
        float4 av = {0.f, 0.f, 0.f, 0.f};
        if (m0 + a_row < N_NODES)
            av = *(const float4*)(A + (size_t)(m0 + a_row) * D + kk + a_k4);
        As[a_k4 + 0][a_row] = av.x;
        As[a_k4 + 1][a_row] = av.y;
        As[a_k4 + 2][a_row] = av.z;
        As[a_k4 + 3][a_row] = av.w;
        *(float4*)&Bs[b_row][b_n4] =
            *(const float4*)(B + (size_t)(kk + b_row) * D + n0 + b_n4);
        __syncthreads();
#pragma unroll
        for (int k = 0; k < 16; ++k) {
            float a[4], b[4];
#pragma unroll
            for (int i = 0; i < 4; ++i) a[i] = As[k][ty * 4 + i];
#pragma unroll
            for (int j = 0; j < 4; ++j) b[j] = Bs[k][tx * 4 + j];
#pragma unroll
            for (int i = 0; i < 4; ++i)
#pragma unroll
                for (int j = 0; j < 4; ++j) acc[i][j] += a[i] * b[j];
        }
        __syncthreads();
    }

#pragma unroll
    for (int i = 0; i < 4; ++i) {
        int m = m0 + ty * 4 + i;
        if (m < N_NODES) {
            float4 r;
            r.x = acc[i][0] + bias[n0 + tx * 4 + 0];
            r.y = acc[i][1] + bias[n0 + tx * 4 + 1];
            r.z = acc[i][2] + bias[n0 + tx * 4 + 2];
            r.w = acc[i][3] + bias[n0 + tx * 4 + 3];
            if (relu) {
                r.x = fmaxf(r.x, 0.f); r.y = fmaxf(r.y, 0.f);
                r.z = fmaxf(r.z, 0.f); r.w = fmaxf(r.w, 0.f);
            }
            *(float4*)(out + (size_t)m * D + n0 + tx * 4) = r;
        }
    }
}

// ---------------------------------------------------------------------------
extern "C" void kernel_launch(void* const* d_in, const int* in_sizes, int n_in,
                              void* d_out, int out_size, void* d_ws, size_t ws_size,
                              hipStream_t stream) {
    const float* x    = (const float*)d_in[0];
    const int*   ei   = (const int*)d_in[1];   // int32 on device!
    const float* W_l1 = (const float*)d_in[2];
    const float* b1   = (const float*)d_in[3];
    const float* W_r1 = (const float*)d_in[4];
    const float* W_l2 = (const float*)d_in[5];
    const float* b2   = (const float*)d_in[6];
    const float* W_r2 = (const float*)d_in[7];
    float* out = (float*)d_out;

    const int* src = ei;
    const int* tgt = ei + N_EDGES;

    // workspace carve-up (256B aligned)
    char* w = (char*)d_ws;
    size_t o = 0;
    auto alloc = [&](size_t bytes) {
        size_t p = o;
        o = (o + bytes + 255) & ~(size_t)255;
        return p;
    };
    int*   cnt        = (int*)(w + alloc((size_t)N_NODES * 4));
    int*   offs       = (int*)(w + alloc((size_t)(N_NODES + 1) * 4));
    int*   cursor     = (int*)(w + alloc((size_t)N_NODES * 4));
    int*   bsum       = (int*)(w + alloc(512 * 4));
    int*   sorted_src = (int*)(w + alloc((size_t)N_EDGES * 4));
    float* agg        = (float*)(w + alloc((size_t)N_NODES * D * 4));
    float* h          = (float*)(w + alloc((size_t)N_NODES * D * 4));
    (void)ws_size; (void)in_sizes; (void)n_in; (void)out_size;

    hipMemsetAsync(cnt, 0, (size_t)N_NODES * 4, stream);

    const int EB = (N_EDGES + 255) / 256;  // 12500
    count_kernel<<<EB, 256, 0, stream>>>(tgt, cnt);
    scan1_kernel<<<SCAN_BLOCKS, 256, 0, stream>>>(cnt, offs, bsum);
    scan2_kernel<<<1, 512, 0, stream>>>(bsum);
    scan3_kernel<<<SCAN_BLOCKS, 256, 0, stream>>>(offs, bsum);
    cursor_kernel<<<SCAN_BLOCKS, 256, 0, stream>>>(offs, cursor);
    fill_kernel<<<EB, 256, 0, stream>>>(src, tgt, cursor, sorted_src);

    const int AGG_B = (N_NODES + 3) / 4;   // 25000 blocks, 4 nodes/block
    dim3 ggrid(4, (N_NODES + 63) / 64);    // (4, 1563)

    // Layer 1: agg1 = mean(x); h = relu([agg1|x] @ [W_l1;W_r1] + b1)
    aggregate_kernel<<<AGG_B, 256, 0, stream>>>(x, agg, offs, sorted_src);
    gemm_fused<<<ggrid, 256, 0, stream>>>(agg, x, W_l1, W_r1, b1, h, 1);

    // Layer 2: agg2 = mean(h); out = [agg2|h] @ [W_l2;W_r2] + b2
    aggregate_kernel<<<AGG_B, 256, 0, stream>>>(h, agg, offs, sorted_src);
    gemm_fused<<<ggrid, 256, 0, stream>>>(agg, h, W_l2, W_r2, b2, out, 0);
}

// Round 3
// 1395.990 us; speedup vs baseline: 1.5235x; 1.5235x over previous
//
#include <hip/hip_runtime.h>
#include <hip/hip_bf16.h>
#include <cstdint>
#include <cstddef>

#define N_NODES 100000
#define N_EDGES 3200000
#define D 256
#define SCAN_BLOCKS 391   // ceil(100000/256)

typedef __attribute__((ext_vector_type(8))) short short8;   // 8 bf16 = 4 VGPRs
typedef __attribute__((ext_vector_type(4))) float f32x4;

__device__ inline unsigned short f2bf(float f) {            // RNE fp32->bf16
    unsigned int u = __float_as_uint(f);
    u += 0x7FFFu + ((u >> 16) & 1u);
    return (unsigned short)(u >> 16);
}
__device__ inline float bf2f(unsigned short h) {
    return __uint_as_float(((unsigned int)h) << 16);
}

// ---------------------------------------------------------------------------
// CSR build: count -> scan -> fill    (edge_index arrives as int32!)
// ---------------------------------------------------------------------------
__global__ void count_kernel(const int* __restrict__ tgt, int* __restrict__ cnt) {
    int e = blockIdx.x * blockDim.x + threadIdx.x;
    if (e < N_EDGES) {
        int t = tgt[e];
        if (t >= 0 && t < N_NODES) atomicAdd(&cnt[t], 1);
    }
}

__global__ void scan1_kernel(const int* __restrict__ cnt, int* __restrict__ offs,
                             int* __restrict__ bsum) {
    __shared__ int s[256];
    int t = threadIdx.x;
    int i = blockIdx.x * 256 + t;
    int v = (i < N_NODES) ? cnt[i] : 0;
    s[t] = v;
    __syncthreads();
    for (int d = 1; d < 256; d <<= 1) {
        int x = (t >= d) ? s[t - d] : 0;
        __syncthreads();
        s[t] += x;
        __syncthreads();
    }
    if (i < N_NODES) offs[i + 1] = s[t];
    if (t == 255) bsum[blockIdx.x] = s[255];
}

__global__ void scan2_kernel(int* __restrict__ bsum) {
    __shared__ int s[512];
    int t = threadIdx.x;
    int v = (t < SCAN_BLOCKS) ? bsum[t] : 0;
    s[t] = v;
    __syncthreads();
    for (int d = 1; d < 512; d <<= 1) {
        int x = (t >= d) ? s[t - d] : 0;
        __syncthreads();
        s[t] += x;
        __syncthreads();
    }
    if (t < SCAN_BLOCKS) bsum[t] = (t == 0) ? 0 : s[t - 1];
}

__global__ void scan3_kernel(int* __restrict__ offs, const int* __restrict__ bsum) {
    int t = threadIdx.x;
    int i = blockIdx.x * 256 + t;
    if (i < N_NODES) offs[i + 1] += bsum[blockIdx.x];
    if (i == 0) offs[0] = 0;
}

__global__ void cursor_kernel(const int* __restrict__ offs, int* __restrict__ cursor) {
    int i = blockIdx.x * 256 + threadIdx.x;
    if (i < N_NODES) cursor[i] = offs[i];
}

__global__ void fill_kernel(const int* __restrict__ src,
                            const int* __restrict__ tgt,
                            int* __restrict__ cursor, int* __restrict__ sorted_src) {
    int e = blockIdx.x * blockDim.x + threadIdx.x;
    if (e < N_EDGES) {
        int t = tgt[e];
        int s = src[e];
        if (t >= 0 && t < N_NODES && s >= 0 && s < N_NODES) {
            int p = atomicAdd(&cursor[t], 1);
            sorted_src[p] = s;
        }
    }
}

// ---------------------------------------------------------------------------
// fp32 -> bf16 bulk convert (8 elements / thread)
// ---------------------------------------------------------------------------
__global__ __launch_bounds__(256) void convert_kernel(const float* __restrict__ in,
                                                      unsigned short* __restrict__ out,
                                                      int n8) {
    int i = blockIdx.x * 256 + threadIdx.x;
    if (i >= n8) return;
    const float4 a = ((const float4*)in)[i * 2 + 0];
    const float4 b = ((const float4*)in)[i * 2 + 1];
    short8 v;
    v[0] = (short)f2bf(a.x); v[1] = (short)f2bf(a.y);
    v[2] = (short)f2bf(a.z); v[3] = (short)f2bf(a.w);
    v[4] = (short)f2bf(b.x); v[5] = (short)f2bf(b.y);
    v[6] = (short)f2bf(b.z); v[7] = (short)f2bf(b.w);
    ((short8*)out)[i] = v;
}

// ---------------------------------------------------------------------------
// Pack B=[Wl;Wr] (512x256 fp32 row-major) into MFMA B-fragment order, bf16.
// Bp[((ntile*16 + kb)*64 + lane)*8 + j] = B[kb*32 + (lane>>4)*8 + j][ntile*16 + (lane&15)]
// ---------------------------------------------------------------------------
__global__ __launch_bounds__(256) void pack_b_kernel(const float* __restrict__ Wl,
                                                     const float* __restrict__ Wr,
                                                     unsigned short* __restrict__ Bp) {
    int t = blockIdx.x * 256 + threadIdx.x;   // 16*16*64 = 16384
    if (t >= 16384) return;
    int lane = t & 63, kb = (t >> 6) & 15, ntile = t >> 10;
    int n = ntile * 16 + (lane & 15);
    int kbase = kb * 32 + (lane >> 4) * 8;
    short8 v;
#pragma unroll
    for (int j = 0; j < 8; ++j) {
        int k = kbase + j;
        const float* W = (k < 256) ? Wl : Wr;
        v[j] = (short)f2bf(W[(size_t)(k & 255) * D + n]);
    }
    ((short8*)Bp)[t] = v;
}

// ---------------------------------------------------------------------------
// Mean aggregation over bf16 rows: one wave per node, lane covers 4 bf16 (8 B)
// ---------------------------------------------------------------------------
__global__ __launch_bounds__(256) void aggregate_bf16(
    const unsigned short* __restrict__ in, unsigned short* __restrict__ out,
    const int* __restrict__ offs, const int* __restrict__ sorted_src) {
    int node = blockIdx.x * 4 + (threadIdx.x >> 6);
    if (node >= N_NODES) return;
    int lane = threadIdx.x & 63;
    int beg = offs[node], end = offs[node + 1];
    float a0 = 0.f, a1 = 0.f, a2 = 0.f, a3 = 0.f;
    for (int j = beg; j < end; ++j) {
        int s = sorted_src[j];
        ushort4 v = *(const ushort4*)(in + (size_t)s * D + lane * 4);
        a0 += bf2f(v.x); a1 += bf2f(v.y); a2 += bf2f(v.z); a3 += bf2f(v.w);
    }
    float inv = 1.0f / fmaxf((float)(end - beg), 1.0f);
    ushort4 r;
    r.x = f2bf(a0 * inv); r.y = f2bf(a1 * inv);
    r.z = f2bf(a2 * inv); r.w = f2bf(a3 * inv);
    *(ushort4*)(out + (size_t)node * D + lane * 4) = r;
}

// ---------------------------------------------------------------------------
// MFMA GEMM: out = [A0 | A1] @ Bp + bias, K=512, optional ReLU, bf16/fp32 out.
// 256 thr = 4 waves; tile BM=128,BN=128,BK=32; each wave does 64x64 via 4x4
// of 16x16x32 MFMAs. A staged in LDS (padded); B fragments read straight from
// the packed 256 KB (L2-resident) buffer.
// ---------------------------------------------------------------------------
__global__ __launch_bounds__(256) void gemm_mfma(
    const unsigned short* __restrict__ A0, const unsigned short* __restrict__ A1,
    const unsigned short* __restrict__ Bp, const float* __restrict__ bias,
    void* __restrict__ outp, int relu, int out_bf16) {
    __shared__ unsigned short As[128][40];   // +8 pad: 80 B row stride
    const int m0 = blockIdx.y * 128;
    const int n0 = blockIdx.x * 128;
    const int t = threadIdx.x;
    const int wave = t >> 6, lane = t & 63;
    const int wy = wave >> 1, wx = wave & 1;
    const int quad = lane >> 4, l16 = lane & 15;

    const int arow = t >> 1;            // 0..127
    const int ahalf = (t & 1) * 16;     // 0 / 16 (bf16 elems)

    f32x4 acc[4][4] = {};

    for (int kb = 0; kb < 16; ++kb) {
        const int k0 = kb * 32;
        const unsigned short* A = (k0 < 256) ? A0 : A1;
        const int kk = k0 & 255;

        short8 v0 = {}, v1 = {};
        if (m0 + arow < N_NODES) {
            const unsigned short* p = A + (size_t)(m0 + arow) * D + kk + ahalf;
            v0 = *(const short8*)p;
            v1 = *(const short8*)(p + 8);
        }
        *(short8*)&As[arow][ahalf + 0] = v0;
        *(short8*)&As[arow][ahalf + 8] = v1;
        __syncthreads();

        short8 af[4], bf[4];
#pragma unroll
        for (int mi = 0; mi < 4; ++mi)
            af[mi] = *(const short8*)&As[wy * 64 + mi * 16 + l16][quad * 8];
#pragma unroll
        for (int ni = 0; ni < 4; ++ni) {
            int ntile = (n0 >> 4) + wx * 4 + ni;
            bf[ni] = ((const short8*)Bp)[(size_t)(ntile * 16 + kb) * 64 + lane];
        }
#pragma unroll
        for (int mi = 0; mi < 4; ++mi)
#pragma unroll
            for (int ni = 0; ni < 4; ++ni)
                acc[mi][ni] = __builtin_amdgcn_mfma_f32_16x16x32_bf16(
                    af[mi], bf[ni], acc[mi][ni], 0, 0, 0);
        __syncthreads();
    }

    unsigned short* ob = (unsigned short*)outp;
    float* of = (float*)outp;
#pragma unroll
    for (int ni = 0; ni < 4; ++ni) {
        const int col = n0 + wx * 64 + ni * 16 + l16;
        const float bcol = bias[col];
#pragma unroll
        for (int mi = 0; mi < 4; ++mi) {
#pragma unroll
            for (int r = 0; r < 4; ++r) {
                int row = m0 + wy * 64 + mi * 16 + quad * 4 + r;
                if (row < N_NODES) {
                    float v = acc[mi][ni][r] + bcol;
                    if (relu) v = fmaxf(v, 0.f);
                    if (out_bf16) ob[(size_t)row * D + col] = f2bf(v);
                    else          of[(size_t)row * D + col] = v;
                }
            }
        }
    }
}

// ---------------------------------------------------------------------------
extern "C" void kernel_launch(void* const* d_in, const int* in_sizes, int n_in,
                              void* d_out, int out_size, void* d_ws, size_t ws_size,
                              hipStream_t stream) {
    const float* x    = (const float*)d_in[0];
    const int*   ei   = (const int*)d_in[1];   // int32 on device!
    const float* W_l1 = (const float*)d_in[2];
    const float* b1   = (const float*)d_in[3];
    const float* W_r1 = (const float*)d_in[4];
    const float* W_l2 = (const float*)d_in[5];
    const float* b2   = (const float*)d_in[6];
    const float* W_r2 = (const float*)d_in[7];
    float* out = (float*)d_out;

    const int* src = ei;
    const int* tgt = ei + N_EDGES;

    char* w = (char*)d_ws;
    size_t o = 0;
    auto alloc = [&](size_t bytes) {
        size_t p = o;
        o = (o + bytes + 255) & ~(size_t)255;
        return p;
    };
    int* cnt        = (int*)(w + alloc((size_t)N_NODES * 4));
    int* offs       = (int*)(w + alloc((size_t)(N_NODES + 1) * 4));
    int* cursor     = (int*)(w + alloc((size_t)N_NODES * 4));
    int* bsum       = (int*)(w + alloc(512 * 4));
    int* sorted_src = (int*)(w + alloc((size_t)N_EDGES * 4));
    unsigned short* xb   = (unsigned short*)(w + alloc((size_t)N_NODES * D * 2));
    unsigned short* hb   = (unsigned short*)(w + alloc((size_t)N_NODES * D * 2));
    unsigned short* aggb = (unsigned short*)(w + alloc((size_t)N_NODES * D * 2));
    unsigned short* Bp1  = (unsigned short*)(w + alloc((size_t)512 * D * 2));
    unsigned short* Bp2  = (unsigned short*)(w + alloc((size_t)512 * D * 2));
    (void)ws_size; (void)in_sizes; (void)n_in; (void)out_size;

    hipMemsetAsync(cnt, 0, (size_t)N_NODES * 4, stream);

    const int EB = (N_EDGES + 255) / 256;
    count_kernel<<<EB, 256, 0, stream>>>(tgt, cnt);
    scan1_kernel<<<SCAN_BLOCKS, 256, 0, stream>>>(cnt, offs, bsum);
    scan2_kernel<<<1, 512, 0, stream>>>(bsum);
    scan3_kernel<<<SCAN_BLOCKS, 256, 0, stream>>>(offs, bsum);
    cursor_kernel<<<SCAN_BLOCKS, 256, 0, stream>>>(offs, cursor);
    fill_kernel<<<EB, 256, 0, stream>>>(src, tgt, cursor, sorted_src);

    // bf16 conversions / weight packing
    const int n8 = N_NODES * D / 8;            // 3.2M
    convert_kernel<<<(n8 + 255) / 256, 256, 0, stream>>>(x, xb, n8);
    pack_b_kernel<<<64, 256, 0, stream>>>(W_l1, W_r1, Bp1);
    pack_b_kernel<<<64, 256, 0, stream>>>(W_l2, W_r2, Bp2);

    const int AGG_B = (N_NODES + 3) / 4;
    dim3 ggrid(2, (N_NODES + 127) / 128);      // (2, 782)

    // Layer 1
    aggregate_bf16<<<AGG_B, 256, 0, stream>>>(xb, aggb, offs, sorted_src);
    gemm_mfma<<<ggrid, 256, 0, stream>>>(aggb, xb, Bp1, b1, hb, 1, 1);

    // Layer 2
    aggregate_bf16<<<AGG_B, 256, 0, stream>>>(hb, aggb, offs, sorted_src);
    gemm_mfma<<<ggrid, 256, 0, stream>>>(aggb, hb, Bp2, b2, out, 0, 0);
}